// Round 10
// baseline (268.551 us; speedup 1.0000x reference)
//
#include <hip/hip_runtime.h>
#include <hip/hip_bf16.h>
#include <stdint.h>

#define M_TOT 16384
#define N_TOT 3072
#define K_TOT 768
#define NT 24            // K-tiles of 32

typedef __attribute__((ext_vector_type(8))) short short8;
typedef __attribute__((ext_vector_type(4))) float f32x4;

__device__ __forceinline__ unsigned short f2bf(float f) {
    union { float f; unsigned u; } v;
    v.f = f;
    unsigned r = v.u + 0x7FFFu + ((v.u >> 16) & 1u);  // round-to-nearest-even
    return (unsigned short)(r >> 16);
}

// ---------------- kernel 1: x fp32 -> bf16 (vectorized) ----------------------
__global__ __launch_bounds__(256) void cvt_x_kernel(const float* __restrict__ x,
                                                    unsigned short* __restrict__ xb,
                                                    int n8) {
    int i = blockIdx.x * blockDim.x + threadIdx.x;
    int stride = gridDim.x * blockDim.x;
    const float4* xv = reinterpret_cast<const float4*>(x);
    uint4* ov = reinterpret_cast<uint4*>(xb);
    for (; i < n8; i += stride) {
        float4 a = xv[2 * i], b = xv[2 * i + 1];
        uint4 o;
        o.x = (unsigned)f2bf(a.x) | ((unsigned)f2bf(a.y) << 16);
        o.y = (unsigned)f2bf(a.z) | ((unsigned)f2bf(a.w) << 16);
        o.z = (unsigned)f2bf(b.x) | ((unsigned)f2bf(b.y) << 16);
        o.w = (unsigned)f2bf(b.z) | ((unsigned)f2bf(b.w) << 16);
        ov[i] = o;
    }
}

// ---------------- kernel 2a: W_tilde = A @ B (2048x1152x64, fp32) ------------
// A-load now COALESCED (row-major float4) + LDS-transpose; round-9 profile
// showed the stride-256B gather left the kernel latency-bound (VALUBusy 0.3%).
__global__ __launch_bounds__(256) void wtilde_gemm_kernel(const float* __restrict__ Af,
                                                          const float* __restrict__ Bf,
                                                          float* __restrict__ Wtmp) {
    __shared__ float As[64][68];   // k-major after transpose; 68 keeps 16B align
    __shared__ float Bs[64][68];
    const int tid = threadIdx.x;
    const int bp = blockIdx.x / 18, bq = blockIdx.x % 18;
    const int p0 = bp * 64, q0 = bq * 64;
    {
        #pragma unroll
        for (int i = 0; i < 4; ++i) {
            int idx = i * 256 + tid;
            int row = idx >> 4, c4 = (idx & 15) * 4;
            f32x4 v = *reinterpret_cast<const f32x4*>(&Af[(size_t)(p0 + row) * 64 + c4]);
            As[c4 + 0][row] = v[0]; As[c4 + 1][row] = v[1];
            As[c4 + 2][row] = v[2]; As[c4 + 3][row] = v[3];
        }
    }
    {
        #pragma unroll
        for (int l = 0; l < 4; ++l) {
            int idx = l * 256 + tid;
            int k = idx >> 4, c4 = (idx & 15) * 4;
            *reinterpret_cast<f32x4*>(&Bs[k][c4]) =
                *reinterpret_cast<const f32x4*>(&Bf[(size_t)k * 1152 + q0 + c4]);
        }
    }
    __syncthreads();
    float acc[4][4] = {};
    const int rb = (tid >> 4) * 4;
    const int cb = (tid & 15) * 4;
    #pragma unroll
    for (int k = 0; k < 64; ++k) {
        f32x4 a = *reinterpret_cast<const f32x4*>(&As[k][rb]);
        f32x4 b = *reinterpret_cast<const f32x4*>(&Bs[k][cb]);
        #pragma unroll
        for (int i = 0; i < 4; ++i)
            #pragma unroll
            for (int j = 0; j < 4; ++j)
                acc[i][j] = fmaf(a[i], b[j], acc[i][j]);
    }
    #pragma unroll
    for (int i = 0; i < 4; ++i) {
        f32x4 o = {acc[i][0], acc[i][1], acc[i][2], acc[i][3]};
        *reinterpret_cast<f32x4*>(&Wtmp[(size_t)(p0 + rb + i) * 1152 + q0 + cb]) = o;
    }
}

// ---------------- kernel 2b: Kronecker permute + Sparse + bf16 + transpose ---
__global__ __launch_bounds__(256) void permute_w_kernel(const float* __restrict__ Wtmp,
                                                        const float* __restrict__ Sp,
                                                        unsigned short* __restrict__ Wt) {
    __shared__ float T[64][65];
    const int tid = threadIdx.x;
    const int r0 = (blockIdx.x % 12) * 64;
    const int c0 = (blockIdx.x / 12) * 64;
    #pragma unroll
    for (int l = 0; l < 16; ++l) {
        int i = l * 4 + (tid >> 6);
        int j = tid & 63;
        int r = r0 + i, c = c0 + j;
        int m1 = r / 24, m2 = r - m1 * 24;
        int n1 = c / 48, n2 = c - n1 * 48;
        T[i][j] = Wtmp[(size_t)(m1 * 64 + n1) * 1152 + m2 * 48 + n2]
                + Sp[(size_t)r * 3072 + c];
    }
    __syncthreads();
    #pragma unroll
    for (int u0 = 0; u0 < 2; ++u0) {
        int u = u0 * 256 + tid;
        int jj = u >> 3;
        int ii = u & 7;
        unsigned w[4];
        #pragma unroll
        for (int t = 0; t < 4; ++t) {
            unsigned lo = f2bf(T[ii * 8 + 2 * t][jj]);
            unsigned hi = f2bf(T[ii * 8 + 2 * t + 1][jj]);
            w[t] = lo | (hi << 16);
        }
        uint4 o = {w[0], w[1], w[2], w[3]};
        *reinterpret_cast<uint4*>(&Wt[(size_t)(c0 + jj) * 768 + r0 + ii * 8]) = o;
    }
}

// ---------------- kernel 3: flatmm — NO LDS, global->VGPR streaming ----------
// A [16384][768] bf16, Bt [3072][768] bf16, C = A@Bt^T + bias.
// 4 independent waves/block, each owns a 128x64 output tile; 2-tile-deep
// register double-buffer; no barriers, no LDS -> waves free-run and de-phase,
// loads hide under co-resident waves' MFMAs.  Rationale: six LDS-staged
// schedules all hit 112-121us; per-tile LDS traffic (96KB rd + 32KB wr per CU
// vs 128B/clk) co-limits with MFMA and is schedule-invariant.  Streaming from
// L2/L3 removes that pipe entirely.
__global__ __launch_bounds__(256, 2) void gemm_bt_kernel(
    const unsigned short* __restrict__ A, const unsigned short* __restrict__ Bt,
    const float* __restrict__ bias, float* __restrict__ C) {
    const int tid = threadIdx.x;
    const int lane = tid & 63;
    const int w = tid >> 6;        // 0..3: wave's N-quarter

    // grid 1536 = 8 XCD x (12 bn x 16 bm); bn-outer within XCD so the
    // concurrent per-XCD set (32 blocks = 2bn x 16bm) touches ~3.8MB <= L2.
    const int xcd = blockIdx.x & 7, g = blockIdx.x >> 3;
    const int bn = g >> 4;                 // 0..11
    const int bm = (xcd << 4) + (g & 15);  // 0..127
    const int brow = bm * 128;
    const int bcol = bn * 256 + w * 64;

    const int la = lane & 15, g4 = lane >> 4;

    // per-lane fragment bases: frag m, tile t -> base + m*16*768 + t*32 elems
    const unsigned short* Ab = A + (size_t)(brow + la) * K_TOT + g4 * 8;
    const unsigned short* Bb = Bt + (size_t)(bcol + la) * K_TOT + g4 * 8;

#define LDSET(aset, bset, t) do {                                                \
        _Pragma("unroll")                                                        \
        for (int m_ = 0; m_ < 8; ++m_)                                           \
            aset[m_] = *reinterpret_cast<const short8*>(                         \
                Ab + (size_t)m_ * 16 * K_TOT + (t) * 32);                        \
        _Pragma("unroll")                                                        \
        for (int n_ = 0; n_ < 4; ++n_)                                           \
            bset[n_] = *reinterpret_cast<const short8*>(                         \
                Bb + (size_t)n_ * 16 * K_TOT + (t) * 32); } while (0)

#define MFMA32(aset, bset) do {                                                  \
        __builtin_amdgcn_s_setprio(1);                                           \
        _Pragma("unroll")                                                        \
        for (int m_ = 0; m_ < 8; ++m_)                                           \
            _Pragma("unroll")                                                    \
            for (int n_ = 0; n_ < 4; ++n_)                                       \
                acc[m_][n_] = __builtin_amdgcn_mfma_f32_16x16x32_bf16(           \
                    aset[m_], bset[n_], acc[m_][n_], 0, 0, 0);                   \
        __builtin_amdgcn_s_setprio(0); } while (0)

    f32x4 acc[8][4];
    #pragma unroll
    for (int m = 0; m < 8; ++m)
        #pragma unroll
        for (int n = 0; n < 4; ++n)
            acc[m][n] = (f32x4){0.f, 0.f, 0.f, 0.f};

    short8 a0[8], b0[4], a1[8], b1[4];
    LDSET(a0, b0, 0);
    LDSET(a1, b1, 1);

    // NOTE: refills at t+2 = NT / t+3 = NT+1 read ~1.6KB past the logical
    // panel ends -- still inside d_ws (xb|wt are adjacent), values unused.
    #pragma unroll 1
    for (int t = 0; t < NT; t += 2) {
        MFMA32(a0, b0);                 // tile t    (compiler: vmcnt keeps set1)
        LDSET(a0, b0, t + 2);           // refill for t+2
        MFMA32(a1, b1);                 // tile t+1
        LDSET(a1, b1, t + 3);           // refill for t+3
    }

    // ---- epilogue: C/D layout col = lane&15, row = (lane>>4)*4 + j ----------
    const int rg = g4 * 4;
    #pragma unroll
    for (int n = 0; n < 4; ++n) {
        const int gc = bcol + n * 16 + la;
        const float bv = bias[gc];
        #pragma unroll
        for (int m = 0; m < 8; ++m) {
            const int gr = brow + m * 16 + rg;
            #pragma unroll
            for (int j = 0; j < 4; ++j)
                C[(size_t)(gr + j) * N_TOT + gc] = acc[m][n][j] + bv;
        }
    }
#undef LDSET
#undef MFMA32
}

extern "C" void kernel_launch(void* const* d_in, const int* in_sizes, int n_in,
                              void* d_out, int out_size, void* d_ws, size_t ws_size,
                              hipStream_t stream) {
    const float* x    = (const float*)d_in[0];
    const float* Af   = (const float*)d_in[1];  // [2048][64]
    const float* Bf   = (const float*)d_in[2];  // [64][1152]
    const float* Sp   = (const float*)d_in[3];  // [768][3072]
    const float* bias = (const float*)d_in[4];  // [3072]
    float* out = (float*)d_out;

    unsigned short* xb = (unsigned short*)d_ws;                 // 25,165,824 B
    unsigned short* wt = xb + (size_t)M_TOT * K_TOT;            // + 4,718,592 B
    // W_tilde scratch in d_out's head; GEMM overwrites all of d_out after.
    float* wtmp = (float*)d_out;                                // 9,437,184 B

    hipLaunchKernelGGL(cvt_x_kernel, dim3(2048), dim3(256), 0, stream,
                       x, xb, M_TOT * K_TOT / 8);
    hipLaunchKernelGGL(wtilde_gemm_kernel, dim3(32 * 18), dim3(256), 0, stream,
                       Af, Bf, wtmp);
    hipLaunchKernelGGL(permute_w_kernel, dim3(12 * 48), dim3(256), 0, stream,
                       wtmp, Sp, wt);
    hipLaunchKernelGGL(gemm_bt_kernel, dim3(1536), dim3(256), 0, stream,
                       xb, wt, bias, out);
}

// Round 11
// 151.011 us; speedup vs baseline: 1.7784x; 1.7784x over previous
//
#include <hip/hip_runtime.h>
#include <hip/hip_bf16.h>
#include <stdint.h>

#define M_TOT 16384
#define N_TOT 3072
#define K_TOT 768

#define BM 256
#define BN 256
#define BK 32
#define NT (K_TOT / BK)   // 24 K-tiles

typedef __attribute__((ext_vector_type(8))) short short8;
typedef __attribute__((ext_vector_type(4))) float f32x4;

__device__ __forceinline__ unsigned short f2bf(float f) {
    union { float f; unsigned u; } v;
    v.f = f;
    unsigned r = v.u + 0x7FFFu + ((v.u >> 16) & 1u);  // round-to-nearest-even
    return (unsigned short)(r >> 16);
}

// ---------------- kernel 1: x fp32 -> bf16 (vectorized) ----------------------
__global__ __launch_bounds__(256) void cvt_x_kernel(const float* __restrict__ x,
                                                    unsigned short* __restrict__ xb,
                                                    int n8) {
    int i = blockIdx.x * blockDim.x + threadIdx.x;
    int stride = gridDim.x * blockDim.x;
    const float4* xv = reinterpret_cast<const float4*>(x);
    uint4* ov = reinterpret_cast<uint4*>(xb);
    for (; i < n8; i += stride) {
        float4 a = xv[2 * i], b = xv[2 * i + 1];
        uint4 o;
        o.x = (unsigned)f2bf(a.x) | ((unsigned)f2bf(a.y) << 16);
        o.y = (unsigned)f2bf(a.z) | ((unsigned)f2bf(a.w) << 16);
        o.z = (unsigned)f2bf(b.x) | ((unsigned)f2bf(b.y) << 16);
        o.w = (unsigned)f2bf(b.z) | ((unsigned)f2bf(b.w) << 16);
        ov[i] = o;
    }
}

// ---------------- kernel 2a: W_tilde = A @ B (2048x1152x64, fp32) ------------
// Coalesced A-loads (row-major float4) + LDS transpose.
__global__ __launch_bounds__(256) void wtilde_gemm_kernel(const float* __restrict__ Af,
                                                          const float* __restrict__ Bf,
                                                          float* __restrict__ Wtmp) {
    __shared__ float As[64][68];
    __shared__ float Bs[64][68];
    const int tid = threadIdx.x;
    const int bp = blockIdx.x / 18, bq = blockIdx.x % 18;
    const int p0 = bp * 64, q0 = bq * 64;
    {
        #pragma unroll
        for (int i = 0; i < 4; ++i) {
            int idx = i * 256 + tid;
            int row = idx >> 4, c4 = (idx & 15) * 4;
            f32x4 v = *reinterpret_cast<const f32x4*>(&Af[(size_t)(p0 + row) * 64 + c4]);
            As[c4 + 0][row] = v[0]; As[c4 + 1][row] = v[1];
            As[c4 + 2][row] = v[2]; As[c4 + 3][row] = v[3];
        }
    }
    {
        #pragma unroll
        for (int l = 0; l < 4; ++l) {
            int idx = l * 256 + tid;
            int k = idx >> 4, c4 = (idx & 15) * 4;
            *reinterpret_cast<f32x4*>(&Bs[k][c4]) =
                *reinterpret_cast<const f32x4*>(&Bf[(size_t)k * 1152 + q0 + c4]);
        }
    }
    __syncthreads();
    float acc[4][4] = {};
    const int rb = (tid >> 4) * 4;
    const int cb = (tid & 15) * 4;
    #pragma unroll
    for (int k = 0; k < 64; ++k) {
        f32x4 a = *reinterpret_cast<const f32x4*>(&As[k][rb]);
        f32x4 b = *reinterpret_cast<const f32x4*>(&Bs[k][cb]);
        #pragma unroll
        for (int i = 0; i < 4; ++i)
            #pragma unroll
            for (int j = 0; j < 4; ++j)
                acc[i][j] = fmaf(a[i], b[j], acc[i][j]);
    }
    #pragma unroll
    for (int i = 0; i < 4; ++i) {
        f32x4 o = {acc[i][0], acc[i][1], acc[i][2], acc[i][3]};
        *reinterpret_cast<f32x4*>(&Wtmp[(size_t)(p0 + rb + i) * 1152 + q0 + cb]) = o;
    }
}

// ---------------- kernel 2b: Kronecker permute + Sparse + bf16 + transpose ---
__global__ __launch_bounds__(256) void permute_w_kernel(const float* __restrict__ Wtmp,
                                                        const float* __restrict__ Sp,
                                                        unsigned short* __restrict__ Wt) {
    __shared__ float T[64][65];
    const int tid = threadIdx.x;
    const int r0 = (blockIdx.x % 12) * 64;
    const int c0 = (blockIdx.x / 12) * 64;
    #pragma unroll
    for (int l = 0; l < 16; ++l) {
        int i = l * 4 + (tid >> 6);
        int j = tid & 63;
        int r = r0 + i, c = c0 + j;
        int m1 = r / 24, m2 = r - m1 * 24;
        int n1 = c / 48, n2 = c - n1 * 48;
        T[i][j] = Wtmp[(size_t)(m1 * 64 + n1) * 1152 + m2 * 48 + n2]
                + Sp[(size_t)r * 3072 + c];
    }
    __syncthreads();
    #pragma unroll
    for (int u0 = 0; u0 < 2; ++u0) {
        int u = u0 * 256 + tid;
        int jj = u >> 3;
        int ii = u & 7;
        unsigned w[4];
        #pragma unroll
        for (int t = 0; t < 4; ++t) {
            unsigned lo = f2bf(T[ii * 8 + 2 * t][jj]);
            unsigned hi = f2bf(T[ii * 8 + 2 * t + 1][jj]);
            w[t] = lo | (hi << 16);
        }
        uint4 o = {w[0], w[1], w[2], w[3]};
        *reinterpret_cast<uint4*>(&Wt[(size_t)(c0 + jj) * 768 + r0 + ii * 8]) = o;
    }
}

// ---------------- kernel 3: R4 8-phase loop + swapped-operand f4 epilogue ----
// A  : [16384][768] bf16 row-major; Bt : [3072][768] bf16 row-major
// C = A@Bt^T + bias.  8 waves (2Mx4N), BK=32, 4 LDS buffers, counted vmcnt.
// MFMA operands SWAPPED (mfma(b,a,acc)) so D layout is col=M-row (lane&15),
// row=N-col ((lane>>4)*4+j): each lane stores float4 of 4 consecutive N-cols
// -> 32 dwordx4 stores (16 rows x 64B contiguous each) instead of 128 scalar
// stores (4 rows x 64B) -- kills the half-line RMW (R2: FETCH 114MB vs 30MB
// unique).  Loop is byte-identical to R4's 112us version for a clean A/B.
__device__ __forceinline__ void gld16(const void* g, void* l) {
    __builtin_amdgcn_global_load_lds(
        (const __attribute__((address_space(1))) void*)g,
        (__attribute__((address_space(3))) void*)l, 16, 0, 0);
}

__global__ __launch_bounds__(512, 2) void gemm_bt_kernel(
    const unsigned short* __restrict__ A, const unsigned short* __restrict__ Bt,
    const float* __restrict__ bias, float* __restrict__ C) {
    // 4 buffers x (A 16KB + B 16KB) = 128 KB
    __shared__ unsigned short As[4][BM * BK];
    __shared__ unsigned short Bs[4][BN * BK];

    const int tid = threadIdx.x;
    const int lane = tid & 63;
    const int wid = tid >> 6;      // 0..7
    const int wr = wid >> 2;       // 0..1  (M half)
    const int wc = wid & 3;        // 0..3  (N quarter)

    // XCD-aware swizzle: 768 blocks = 8 XCDs x 96
    const int wg = (blockIdx.x & 7) * 96 + (blockIdx.x >> 3);
    const int bm = wg / (N_TOT / BN), bn = wg % (N_TOT / BN);
    const int brow = bm * BM, bcol = bn * BN;

    // ---- staging geometry (linear LDS dest, pre-swizzled global source) ----
    const int srow = tid >> 2;                                   // 0..127
    const int soff = (((tid & 3) ^ ((tid >> 3) & 3)) << 4);      // bytes
    const char* pA = (const char*)A + ((size_t)(brow + srow) * K_TOT) * 2 + soff;
    const char* pB = (const char*)Bt + ((size_t)(bcol + srow) * K_TOT) * 2 + soff;
    const size_t row128 = (size_t)128 * K_TOT * 2;
    const int tid16 = tid * 16;

#define STAGE_AH(u) do { const char* s_ = pA + (size_t)(u) * (BK * 2);           \
        gld16(s_,          (char*)&As[(u) & 3][0] + tid16);                      \
        gld16(s_ + row128, (char*)&As[(u) & 3][0] + tid16 + 8192); } while (0)
#define STAGE_BH(u) do { const char* s_ = pB + (size_t)(u) * (BK * 2);           \
        gld16(s_,          (char*)&Bs[(u) & 3][0] + tid16);                      \
        gld16(s_ + row128, (char*)&Bs[(u) & 3][0] + tid16 + 8192); } while (0)

    // ---- fragment reads: phys byte = row*64 + ((js ^ ((row>>1)&3))<<4) ------
    const int la = lane & 15;
    const int g4 = lane >> 4;
    const int swb = ((g4 ^ ((lane >> 1) & 3)) << 4);   // byte in row
#define FRAG_A(bu, r) (*(const short8*)((const char*)&As[bu][0] + (r) * 64 + swb))
#define FRAG_B(bu, r) (*(const short8*)((const char*)&Bs[bu][0] + (r) * 64 + swb))

#define LGKM0_FENCE() do {                                                       \
        asm volatile("s_waitcnt lgkmcnt(0)" ::: "memory");                       \
        __builtin_amdgcn_sched_barrier(0); } while (0)

    f32x4 acc[8][4];
    #pragma unroll
    for (int m = 0; m < 8; ++m)
        #pragma unroll
        for (int n = 0; n < 4; ++n)
            acc[m][n] = (f32x4){0.f, 0.f, 0.f, 0.f};

    // prologue: stage tiles 0,1,2 (12 loads/thread); wait tile 0 (8 in flight)
    STAGE_AH(0); STAGE_BH(0);
    STAGE_AH(1); STAGE_BH(1);
    STAGE_AH(2); STAGE_BH(2);
    asm volatile("s_waitcnt vmcnt(8)" ::: "memory");
    __builtin_amdgcn_s_barrier();

    const int arow = wr * 128;
    const int bcolw = wc * 64;
    for (int t = 0; t < NT; ++t) {
        const int bu = t & 3;
        short8 a0[4], b0[4];
        // ================= phase A: quadrant m0-3 x n0-3 =====================
        #pragma unroll
        for (int n = 0; n < 4; ++n) b0[n] = FRAG_B(bu, bcolw + n * 16 + la);
        #pragma unroll
        for (int m = 0; m < 4; ++m) a0[m] = FRAG_A(bu, arow + m * 16 + la);
        if (t < NT - 3) STAGE_AH(t + 3);
        __builtin_amdgcn_s_barrier();
        LGKM0_FENCE();
        __builtin_amdgcn_s_setprio(1);
        #pragma unroll
        for (int m = 0; m < 4; ++m)
            #pragma unroll
            for (int n = 0; n < 4; ++n)
                acc[m][n] = __builtin_amdgcn_mfma_f32_16x16x32_bf16(
                    b0[n], a0[m], acc[m][n], 0, 0, 0);   // SWAPPED operands
        __builtin_amdgcn_s_setprio(0);
        __builtin_amdgcn_s_barrier();
        // ================= phase B: quadrant m4-7 x n0-3 =====================
        #pragma unroll
        for (int m = 0; m < 4; ++m) a0[m] = FRAG_A(bu, arow + 64 + m * 16 + la);
        if (t < NT - 3) STAGE_BH(t + 3);
        if (t < NT - 3)       asm volatile("s_waitcnt vmcnt(8)" ::: "memory");
        else if (t == NT - 3) asm volatile("s_waitcnt vmcnt(4)" ::: "memory");
        else if (t == NT - 2) asm volatile("s_waitcnt vmcnt(0)" ::: "memory");
        __builtin_amdgcn_s_barrier();
        LGKM0_FENCE();
        __builtin_amdgcn_s_setprio(1);
        #pragma unroll
        for (int m = 0; m < 4; ++m)
            #pragma unroll
            for (int n = 0; n < 4; ++n)
                acc[4 + m][n] = __builtin_amdgcn_mfma_f32_16x16x32_bf16(
                    b0[n], a0[m], acc[4 + m][n], 0, 0, 0);   // SWAPPED operands
        __builtin_amdgcn_s_setprio(0);
        __builtin_amdgcn_s_barrier();
    }

    // ---- epilogue: swapped layout -> lane owns M-row (la), 4 N-cols (g4,j) --
    // acc[m][n][j] = C[brow+arow+m*16+la][bcol+bcolw+n*16+g4*4+j]
    #pragma unroll
    for (int n = 0; n < 4; ++n) {
        const int gc = bcol + bcolw + n * 16 + g4 * 4;
        const f32x4 bv = *reinterpret_cast<const f32x4*>(&bias[gc]);
        #pragma unroll
        for (int m = 0; m < 8; ++m) {
            const int gr = brow + arow + m * 16 + la;
            f32x4 o = {acc[m][n][0] + bv[0], acc[m][n][1] + bv[1],
                       acc[m][n][2] + bv[2], acc[m][n][3] + bv[3]};
            *reinterpret_cast<f32x4*>(&C[(size_t)gr * N_TOT + gc]) = o;
        }
    }
#undef STAGE_AH
#undef STAGE_BH
#undef FRAG_A
#undef FRAG_B
#undef LGKM0_FENCE
}

extern "C" void kernel_launch(void* const* d_in, const int* in_sizes, int n_in,
                              void* d_out, int out_size, void* d_ws, size_t ws_size,
                              hipStream_t stream) {
    const float* x    = (const float*)d_in[0];
    const float* Af   = (const float*)d_in[1];  // [2048][64]
    const float* Bf   = (const float*)d_in[2];  // [64][1152]
    const float* Sp   = (const float*)d_in[3];  // [768][3072]
    const float* bias = (const float*)d_in[4];  // [3072]
    float* out = (float*)d_out;

    unsigned short* xb = (unsigned short*)d_ws;                 // 25,165,824 B
    unsigned short* wt = xb + (size_t)M_TOT * K_TOT;            // + 4,718,592 B
    // W_tilde scratch in d_out's head; GEMM overwrites all of d_out after.
    float* wtmp = (float*)d_out;                                // 9,437,184 B

    hipLaunchKernelGGL(cvt_x_kernel, dim3(2048), dim3(256), 0, stream,
                       x, xb, M_TOT * K_TOT / 8);
    hipLaunchKernelGGL(wtilde_gemm_kernel, dim3(32 * 18), dim3(256), 0, stream,
                       Af, Bf, wtmp);
    hipLaunchKernelGGL(permute_w_kernel, dim3(12 * 48), dim3(256), 0, stream,
                       wtmp, Sp, wt);
    hipLaunchKernelGGL(gemm_bt_kernel,
                       dim3((M_TOT / BM) * (N_TOT / BN)), dim3(512),
                       0, stream, xb, wt, bias, out);
}